// Round 16
// baseline (114.782 us; speedup 1.0000x reference)
//
#include <hip/hip_runtime.h>
#include <hip/hip_bf16.h>

#define N_ROWS 8192
#define D_DIM  256

// loss_i = log(sum_{j != i} exp(<x_i,y_j>/T)) - <x_i,y_i>/T ; out = mean_i loss_i
// fp8 e4m3 inputs (scale 64), PLAIN row-major; acc = 4096*<x,y> via MX-scaled
// MFMA 16x16x128 with unit E8M0 scales (exact fp8 dot); 1/4096 in constants.
static constexpr float kQuantScale = 64.0f;
static constexpr float kScaleAcc = 20.609929155556627f / 4096.0f;  // (1/T)*log2(e)/4096
static constexpr float kInvTAcc  = 14.285714285714286f / 4096.0f;  // (1/T)/4096

typedef float f32x4 __attribute__((ext_vector_type(4)));
typedef int   i32x4 __attribute__((ext_vector_type(4)));
typedef int   i32x8 __attribute__((ext_vector_type(8)));

// async 16B global->LDS: LDS dest = wave-uniform base + lane*16
__device__ __forceinline__ void gl_lds16(const void* g, void* l) {
  __builtin_amdgcn_global_load_lds(
      (const __attribute__((address_space(1))) void*)g,
      (__attribute__((address_space(3))) void*)l, 16, 0, 0);
}

// ---------------- fp32 -> fp8 e4m3 pre-convert (plain layout) + ws init --------
__global__ __launch_bounds__(256)
void cvt_fp8_kernel(const float* __restrict__ x, const float* __restrict__ y,
                    unsigned char* __restrict__ xq, unsigned char* __restrict__ yq,
                    float* __restrict__ rowsum, unsigned int* __restrict__ done) {
  if (blockIdx.x == 0) {
    for (int i = threadIdx.x; i < N_ROWS; i += 256) rowsum[i] = 0.f;
    if (threadIdx.x == 0) *done = 0u;
  }
  const int per_mat = N_ROWS * D_DIM / 8;  // 8 elements per thread
  int idx = blockIdx.x * blockDim.x + threadIdx.x;
  const float* src = x;
  unsigned char* dst = xq;
  int i = idx;
  if (idx >= per_mat) { src = y; dst = yq; i = idx - per_mat; }
  float4 a = ((const float4*)src)[2 * (size_t)i];
  float4 b = ((const float4*)src)[2 * (size_t)i + 1];
  int v0 = 0, v1 = 0;
  v0 = __builtin_amdgcn_cvt_pk_fp8_f32(a.x * kQuantScale, a.y * kQuantScale, v0, false);
  v0 = __builtin_amdgcn_cvt_pk_fp8_f32(a.z * kQuantScale, a.w * kQuantScale, v0, true);
  v1 = __builtin_amdgcn_cvt_pk_fp8_f32(b.x * kQuantScale, b.y * kQuantScale, v1, false);
  v1 = __builtin_amdgcn_cvt_pk_fp8_f32(b.z * kQuantScale, b.w * kQuantScale, v1, true);
  *(int2*)(dst + (size_t)i * 8) = make_int2(v0, v1);   // plain row-major
}

// ---------------- fused GEMM(MX-fp8) + exp + row-sum + finalize ----------------
// R16: finer persistence granularity — 1024 blocks (bi=b>>5, gjj=b&31), each
// computes ONE 256x256 super-tile = 2 rounds of 128 cols. Rationale: 256
// 1-per-CU persistent blocks are placement-fragile (a CU handed 2 serializes,
// another idles -> measured Occupancy 17% vs 25% expected, wall ~2x block
// time). 1024 queued blocks backfill idle CUs (imbalance <= 1/4).
// A-fragments register-resident per block (64 VGPRs, loaded once, reused both
// rounds) — halves per-round LDS read traffic. Row-sums in LDS (R14); diag via
// device-scope atomicExch; single-fence ticket finalize (R12); all acc indices
// compile-time (R10); no per-block fences (R4).
__global__ __launch_bounds__(512, 1)
void infonce_gemm(const unsigned char* __restrict__ X,
                  const unsigned char* __restrict__ Y,
                  float* __restrict__ rowsum, float* __restrict__ diag,
                  unsigned int* __restrict__ done, float* __restrict__ out) {
  __shared__ unsigned char Xs[256 * 256];      // 64 KB, X-block full-K
  __shared__ unsigned char Ys[2][128 * 256];   // 2 x 32 KB, Y tile dbuf
  __shared__ float lds_rs[256];                // per-block row sums (local rows)
  __shared__ unsigned int ticket_s;

  const int b   = blockIdx.x;       // 0..1023
  const int bi  = b >> 5;           // 0..31: X-row-block (256 rows)
  const int gjj = b & 31;           // 0..31: col-pair group; ct = gjj*2 + tt

  const int t    = threadIdx.x;
  const int lane = t & 63;
  const int wave = t >> 6;        // 0..7
  const int wm   = wave >> 1;     // 0..3  (64-row band)
  const int wn   = wave & 1;      // 0..1  (64-col half)
  const int quad = lane >> 4;     // 0..3
  const int l15  = lane & 15;

  const unsigned char* Xblk = X + (size_t)(bi * 256) * D_DIM;

  if (t < 256) lds_rs[t] = 0.f;    // visible after the first __syncthreads

  // ---- prologue: stage X (4096 slots of 16B, 8 per thread) ----
#pragma unroll
  for (int it = 0; it < 8; ++it) {
    const int c0  = (it * 8 + wave) * 64;
    const int s   = c0 + lane;
    const int row = s >> 4;                 // 0..255
    const int cg  = (s & 15) ^ (row & 15);  // inverse swizzle on global side
    gl_lds16(Xblk + (size_t)row * D_DIM + cg * 16, &Xs[c0 * 16]);
  }
  // stage Y tile 0 (2048 slots, 4 per thread) into buffer 0
  {
    const unsigned char* Yblk = Y + (size_t)(gjj * 2) * 128 * D_DIM;
#pragma unroll
    for (int it = 0; it < 4; ++it) {
      const int c0  = (it * 8 + wave) * 64;
      const int s   = c0 + lane;
      const int row = s >> 4;                 // 0..127
      const int cg  = (s & 15) ^ (row & 15);
      gl_lds16(Yblk + (size_t)row * D_DIM + cg * 16, &Ys[0][c0 * 16]);
    }
  }

  f32x4 acc[4][4];
#pragma unroll
  for (int a = 0; a < 4; ++a)
#pragma unroll
    for (int c = 0; c < 4; ++c) acc[a][c] = (f32x4){0.f, 0.f, 0.f, 0.f};

  i32x8 a8[4][2];    // A fragments, register-resident across both rounds

  for (int tt = 0; tt < 2; ++tt) {
    const int p = tt;

    __syncthreads();   // X + Y[tt] staged (vmcnt drained by barrier)

    if (tt == 0) {     // stage Y tile 1 into buffer 1 (overlaps round 0 compute)
      const unsigned char* Yblk = Y + (size_t)(gjj * 2 + 1) * 128 * D_DIM;
#pragma unroll
      for (int it = 0; it < 4; ++it) {
        const int c0  = (it * 8 + wave) * 64;
        const int s   = c0 + lane;
        const int row = s >> 4;
        const int cg  = (s & 15) ^ (row & 15);
        gl_lds16(Yblk + (size_t)row * D_DIM + cg * 16, &Ys[1][c0 * 16]);
      }
      // load A fragments once: 16 ds_read_b128 -> 64 VGPRs, reused both rounds
#pragma unroll
      for (int mt = 0; mt < 4; ++mt) {
        const int row = wm * 64 + mt * 16 + l15;
#pragma unroll
        for (int kb = 0; kb < 2; ++kb) {
          const int p0 = (kb * 8 + quad * 2 + 0) ^ (row & 15);
          const int p1 = (kb * 8 + quad * 2 + 1) ^ (row & 15);
          i32x4 lo = *(const i32x4*)(&Xs[row * 256 + p0 * 16]);
          i32x4 hi = *(const i32x4*)(&Xs[row * 256 + p1 * 16]);
          a8[mt][kb] = __builtin_shufflevector(lo, hi, 0, 1, 2, 3, 4, 5, 6, 7);
        }
      }
    }

    // compute: 2 MX k-blocks of 128; B frags from LDS, A from registers
#pragma unroll
    for (int kb = 0; kb < 2; ++kb) {
      i32x8 b8[4];
#pragma unroll
      for (int nt = 0; nt < 4; ++nt) {
        const int row = wn * 64 + nt * 16 + l15;
        const int p0  = (kb * 8 + quad * 2 + 0) ^ (row & 15);
        const int p1  = (kb * 8 + quad * 2 + 1) ^ (row & 15);
        i32x4 lo = *(const i32x4*)(&Ys[p][row * 256 + p0 * 16]);
        i32x4 hi = *(const i32x4*)(&Ys[p][row * 256 + p1 * 16]);
        b8[nt] = __builtin_shufflevector(lo, hi, 0, 1, 2, 3, 4, 5, 6, 7);
      }
#pragma unroll
      for (int mt = 0; mt < 4; ++mt)
#pragma unroll
        for (int nt = 0; nt < 4; ++nt)
          acc[mt][nt] = __builtin_amdgcn_mfma_scale_f32_16x16x128_f8f6f4(
              a8[mt][kb], b8[nt], acc[mt][nt],
              0, 0,                    // cbsz=fp8 e4m3, blgp=fp8 e4m3
              0, 0x7F7F7F7F,           // A scales = 1.0 (E8M0 127)
              0, 0x7F7F7F7F);          // B scales = 1.0
    }

    // ---- tile epilogue: exp + row-sum into LDS (lgkm domain, R14) ----
#pragma unroll
    for (int mt = 0; mt < 4; ++mt) {
#pragma unroll
      for (int rr = 0; rr < 4; ++rr) {
        float part = 0.f;
#pragma unroll
        for (int nt = 0; nt < 4; ++nt)
          part += __builtin_amdgcn_exp2f(acc[mt][nt][rr] * kScaleAcc);
        part += __shfl_xor(part, 1);
        part += __shfl_xor(part, 2);
        part += __shfl_xor(part, 4);
        part += __shfl_xor(part, 8);
        if (l15 == 0)
          atomicAdd(&lds_rs[wm * 64 + mt * 16 + quad * 4 + rr], part);
      }
    }
    // diagonal: col-tile ct overlaps rows iff ct==2*bi (wm==wn) or 2*bi+1
    // (wm==wn+2). Device-scope atomicExch so the last block reads coherently.
    {
      const int ct = gjj * 2 + tt;
      const bool d0 = (ct == 2 * bi)     && (wm == wn);
      const bool d1 = (ct == 2 * bi + 1) && (wm == wn + 2);
      if (d0 || d1) {
        const int gi_base = bi * 256 + wm * 64;
#pragma unroll
        for (int nt = 0; nt < 4; ++nt)
#pragma unroll
          for (int rr = 0; rr < 4; ++rr)
            if (l15 == quad * 4 + rr)
              atomicExch(&diag[gi_base + nt * 16 + l15], acc[nt][nt][rr]);
      }
    }
#pragma unroll
    for (int a = 0; a < 4; ++a)
#pragma unroll
      for (int c = 0; c < 4; ++c) acc[a][c] = (f32x4){0.f, 0.f, 0.f, 0.f};
  }

  // ---- flush LDS row sums to global (one atomic per row, off critical path) ----
  __syncthreads();                       // lds_rs complete
  if (t < 256) atomicAdd(&rowsum[bi * 256 + t], lds_rs[t]);

  // ---- last-block finalize (single fence — R12-validated) ----
  __syncthreads();                       // drains this block's atomics (vmcnt)
  if (t == 0) ticket_s = atomicAdd(done, 1u);
  __syncthreads();
  if (ticket_s == 1023u) {
    __threadfence();                     // one acquire, one block only
    float local = 0.f;
    for (int i = t; i < N_ROWS; i += 512) {
      const float rs = atomicAdd(&rowsum[i], 0.0f);   // device-coherent read
      const float d  = atomicAdd(&diag[i], 0.0f);
      local += __logf(rs - __builtin_amdgcn_exp2f(d * kScaleAcc)) - d * kInvTAcc;
    }
    float* red = (float*)Xs;
    red[t] = local;
    __syncthreads();
    for (int s2 = 256; s2 > 0; s2 >>= 1) {
      if (t < s2) red[t] += red[t + s2];
      __syncthreads();
    }
    if (t == 0) out[0] = red[0] / (float)N_ROWS;
  }
}

extern "C" void kernel_launch(void* const* d_in, const int* in_sizes, int n_in,
                              void* d_out, int out_size, void* d_ws, size_t ws_size,
                              hipStream_t stream) {
  const float* x = (const float*)d_in[0];
  const float* y = (const float*)d_in[1];
  float* out = (float*)d_out;

  // ws layout: rowsum[N] f32 | diag[N] f32 | done u32(+pad) | xq | yq
  float* rowsum = (float*)d_ws;
  float* diag   = rowsum + N_ROWS;
  unsigned int* done = (unsigned int*)(diag + N_ROWS);
  unsigned char* xq = (unsigned char*)d_ws + 2 * N_ROWS * sizeof(float) + 16;
  unsigned char* yq = xq + (size_t)N_ROWS * D_DIM;

  int cvt_blocks = 2 * N_ROWS * D_DIM / 8 / 256;  // 2048
  cvt_fp8_kernel<<<cvt_blocks, 256, 0, stream>>>(x, y, xq, yq, rowsum, done);

  infonce_gemm<<<1024, 512, 0, stream>>>(xq, yq, rowsum, diag, done, out);
}

// Round 17
// 100.961 us; speedup vs baseline: 1.1369x; 1.1369x over previous
//
#include <hip/hip_runtime.h>
#include <hip/hip_bf16.h>

#define N_ROWS 8192
#define D_DIM  256

// loss_i = log(sum_{j != i} exp(<x_i,y_j>/T)) - <x_i,y_i>/T ; out = mean_i loss_i
// fp8 e4m3 inputs (scale 64), PLAIN row-major; acc = 4096*<x,y> via MX-scaled
// MFMA 16x16x128 with unit E8M0 scales (exact fp8 dot); 1/4096 in constants.
static constexpr float kQuantScale = 64.0f;
static constexpr float kScaleAcc = 20.609929155556627f / 4096.0f;  // (1/T)*log2(e)/4096
static constexpr float kInvTAcc  = 14.285714285714286f / 4096.0f;  // (1/T)/4096

typedef float f32x4 __attribute__((ext_vector_type(4)));
typedef int   i32x4 __attribute__((ext_vector_type(4)));
typedef int   i32x8 __attribute__((ext_vector_type(8)));

// async 16B global->LDS: LDS dest = wave-uniform base + lane*16
__device__ __forceinline__ void gl_lds16(const void* g, void* l) {
  __builtin_amdgcn_global_load_lds(
      (const __attribute__((address_space(1))) void*)g,
      (__attribute__((address_space(3))) void*)l, 16, 0, 0);
}

// ---------------- fp32 -> fp8 e4m3 pre-convert (plain layout) + ws init --------
__global__ __launch_bounds__(256)
void cvt_fp8_kernel(const float* __restrict__ x, const float* __restrict__ y,
                    unsigned char* __restrict__ xq, unsigned char* __restrict__ yq,
                    float* __restrict__ rowsum, unsigned int* __restrict__ done) {
  if (blockIdx.x == 0) {
    for (int i = threadIdx.x; i < N_ROWS; i += 256) rowsum[i] = 0.f;
    if (threadIdx.x == 0) *done = 0u;
  }
  const int per_mat = N_ROWS * D_DIM / 8;  // 8 elements per thread
  int idx = blockIdx.x * blockDim.x + threadIdx.x;
  const float* src = x;
  unsigned char* dst = xq;
  int i = idx;
  if (idx >= per_mat) { src = y; dst = yq; i = idx - per_mat; }
  float4 a = ((const float4*)src)[2 * (size_t)i];
  float4 b = ((const float4*)src)[2 * (size_t)i + 1];
  int v0 = 0, v1 = 0;
  v0 = __builtin_amdgcn_cvt_pk_fp8_f32(a.x * kQuantScale, a.y * kQuantScale, v0, false);
  v0 = __builtin_amdgcn_cvt_pk_fp8_f32(a.z * kQuantScale, a.w * kQuantScale, v0, true);
  v1 = __builtin_amdgcn_cvt_pk_fp8_f32(b.x * kQuantScale, b.y * kQuantScale, v1, false);
  v1 = __builtin_amdgcn_cvt_pk_fp8_f32(b.z * kQuantScale, b.w * kQuantScale, v1, true);
  *(int2*)(dst + (size_t)i * 8) = make_int2(v0, v1);   // plain row-major
}

// ---------------- persistent fused GEMM(MX-fp8) + exp + row-sum + finalize -----
// R15 chassis (best known): 256 persistent blocks (1/CU), 512 threads = 8
// waves (wm 0..3, wn 0..1). X-block (256 rows, full K) staged once (64 KB);
// Y: 8 tiles of 128 cols full-K double-buffered (64 KB). 8 rounds, one
// barrier per tile. MX MFMA 16x16x128, unit scales (R15-verified).
// R17 CHANGE: row-sum partials accumulate in 16 REGISTERS (psum) across all
// rounds — per-round epilogue is pure VALU (64 exp + adds); the 64 shfl
// (ds_bpermute) + 16 LDS atomics per wave per round are hoisted to ONE
// reduce+flush at block end (they were serializing the shared LDS pipe
// inside the barrier convoy). All acc/psum indices compile-time (R10);
// no per-block fences (R4); single-fence ticket finalize (R12).
__global__ __launch_bounds__(512, 1)
void infonce_gemm(const unsigned char* __restrict__ X,
                  const unsigned char* __restrict__ Y,
                  float* __restrict__ rowsum, float* __restrict__ diag,
                  unsigned int* __restrict__ done, float* __restrict__ out) {
  __shared__ unsigned char Xs[256 * 256];      // 64 KB, X-block full-K
  __shared__ unsigned char Ys[2][128 * 256];   // 2 x 32 KB, Y tile dbuf
  __shared__ unsigned int ticket_s;

  const int b  = blockIdx.x;        // 0..255
  const int bi = b >> 3;            // 0..31: X-row-block (256 rows)
  const int gj = b & 7;             // col-group: col-tile ct = gj*8 + tt

  const int t    = threadIdx.x;
  const int lane = t & 63;
  const int wave = t >> 6;        // 0..7
  const int wm   = wave >> 1;     // 0..3  (64-row band)
  const int wn   = wave & 1;      // 0..1  (64-col half)
  const int quad = lane >> 4;     // 0..3
  const int l15  = lane & 15;

  const unsigned char* Xblk = X + (size_t)(bi * 256) * D_DIM;

  // ---- prologue: stage X (4096 slots of 16B, 8 per thread) ----
#pragma unroll
  for (int it = 0; it < 8; ++it) {
    const int c0  = (it * 8 + wave) * 64;
    const int s   = c0 + lane;
    const int row = s >> 4;                 // 0..255
    const int cg  = (s & 15) ^ (row & 15);  // inverse swizzle on global side
    gl_lds16(Xblk + (size_t)row * D_DIM + cg * 16, &Xs[c0 * 16]);
  }
  // stage Y tile 0 (2048 slots, 4 per thread) into buffer 0
  {
    const unsigned char* Yblk = Y + (size_t)(gj * 8) * 128 * D_DIM;
#pragma unroll
    for (int it = 0; it < 4; ++it) {
      const int c0  = (it * 8 + wave) * 64;
      const int s   = c0 + lane;
      const int row = s >> 4;                 // 0..127
      const int cg  = (s & 15) ^ (row & 15);
      gl_lds16(Yblk + (size_t)row * D_DIM + cg * 16, &Ys[0][c0 * 16]);
    }
  }

  f32x4 acc[4][4];
#pragma unroll
  for (int a = 0; a < 4; ++a)
#pragma unroll
    for (int c = 0; c < 4; ++c) acc[a][c] = (f32x4){0.f, 0.f, 0.f, 0.f};

  float psum[4][4];   // per-lane running row-sum partials (over this lane's cols)
#pragma unroll
  for (int a = 0; a < 4; ++a)
#pragma unroll
    for (int c = 0; c < 4; ++c) psum[a][c] = 0.f;

  for (int tt = 0; tt < 8; ++tt) {
    const int p = tt & 1;

    __syncthreads();   // round tt staged (vmcnt drained by barrier)

    if (tt < 7) {      // stage Y tile tt+1 into the other buffer
      const unsigned char* Yblk = Y + (size_t)(gj * 8 + tt + 1) * 128 * D_DIM;
#pragma unroll
      for (int it = 0; it < 4; ++it) {
        const int c0  = (it * 8 + wave) * 64;
        const int s   = c0 + lane;
        const int row = s >> 4;
        const int cg  = (s & 15) ^ (row & 15);
        gl_lds16(Yblk + (size_t)row * D_DIM + cg * 16, &Ys[p ^ 1][c0 * 16]);
      }
    }

    // full-K compute: 2 MX k-blocks of 128; per kb: 8 frag b128-pairs + 16 MFMA
#pragma unroll
    for (int kb = 0; kb < 2; ++kb) {
      i32x8 a8[4], b8[4];
#pragma unroll
      for (int mt = 0; mt < 4; ++mt) {
        const int row = wm * 64 + mt * 16 + l15;
        const int p0  = (kb * 8 + quad * 2 + 0) ^ (row & 15);
        const int p1  = (kb * 8 + quad * 2 + 1) ^ (row & 15);
        i32x4 lo = *(const i32x4*)(&Xs[row * 256 + p0 * 16]);
        i32x4 hi = *(const i32x4*)(&Xs[row * 256 + p1 * 16]);
        a8[mt] = __builtin_shufflevector(lo, hi, 0, 1, 2, 3, 4, 5, 6, 7);
      }
#pragma unroll
      for (int nt = 0; nt < 4; ++nt) {
        const int row = wn * 64 + nt * 16 + l15;
        const int p0  = (kb * 8 + quad * 2 + 0) ^ (row & 15);
        const int p1  = (kb * 8 + quad * 2 + 1) ^ (row & 15);
        i32x4 lo = *(const i32x4*)(&Ys[p][row * 256 + p0 * 16]);
        i32x4 hi = *(const i32x4*)(&Ys[p][row * 256 + p1 * 16]);
        b8[nt] = __builtin_shufflevector(lo, hi, 0, 1, 2, 3, 4, 5, 6, 7);
      }
#pragma unroll
      for (int mt = 0; mt < 4; ++mt)
#pragma unroll
        for (int nt = 0; nt < 4; ++nt)
          acc[mt][nt] = __builtin_amdgcn_mfma_scale_f32_16x16x128_f8f6f4(
              a8[mt], b8[nt], acc[mt][nt],
              0, 0,                    // cbsz=fp8 e4m3, blgp=fp8 e4m3
              0, 0x7F7F7F7F,           // A scales = 1.0 (E8M0 127)
              0, 0x7F7F7F7F);          // B scales = 1.0
    }

    // ---- epilogue: exp + accumulate into REGISTERS (pure VALU, no shfl/LDS) ----
#pragma unroll
    for (int mt = 0; mt < 4; ++mt) {
#pragma unroll
      for (int rr = 0; rr < 4; ++rr) {
        float part = 0.f;
#pragma unroll
        for (int nt = 0; nt < 4; ++nt)
          part += __builtin_amdgcn_exp2f(acc[mt][nt][rr] * kScaleAcc);
        psum[mt][rr] += part;
      }
    }
    // diagonal: col-tile ct overlaps rows iff ct==2*bi (wm==wn) or 2*bi+1
    // (wm==wn+2). Device-scope atomicExch so the last block reads coherently.
    {
      const int ct = gj * 8 + tt;
      const bool d0 = (ct == 2 * bi)     && (wm == wn);
      const bool d1 = (ct == 2 * bi + 1) && (wm == wn + 2);
      if (d0 || d1) {
        const int gi_base = bi * 256 + wm * 64;
#pragma unroll
        for (int nt = 0; nt < 4; ++nt)
#pragma unroll
          for (int rr = 0; rr < 4; ++rr)
            if (l15 == quad * 4 + rr)
              atomicExch(&diag[gi_base + nt * 16 + l15], acc[nt][nt][rr]);
      }
    }
#pragma unroll
    for (int a = 0; a < 4; ++a)
#pragma unroll
      for (int c = 0; c < 4; ++c) acc[a][c] = (f32x4){0.f, 0.f, 0.f, 0.f};
  }

  // ---- one reduce + flush per block (16 shfl-chains + 16 atomics per wave) ----
  {
    const int gi_base = bi * 256 + wm * 64;
#pragma unroll
    for (int mt = 0; mt < 4; ++mt) {
#pragma unroll
      for (int rr = 0; rr < 4; ++rr) {
        float v = psum[mt][rr];
        v += __shfl_xor(v, 1);
        v += __shfl_xor(v, 2);
        v += __shfl_xor(v, 4);
        v += __shfl_xor(v, 8);
        if (l15 == 0)
          atomicAdd(&rowsum[gi_base + mt * 16 + quad * 4 + rr], v);
      }
    }
  }

  // ---- last-block finalize (single fence — R12-validated) ----
  __syncthreads();                       // drains this block's atomics (vmcnt)
  if (t == 0) ticket_s = atomicAdd(done, 1u);
  __syncthreads();
  if (ticket_s == 255u) {
    __threadfence();                     // one acquire, one block only
    float local = 0.f;
    for (int i = t; i < N_ROWS; i += 512) {
      const float rs = atomicAdd(&rowsum[i], 0.0f);   // device-coherent read
      const float d  = atomicAdd(&diag[i], 0.0f);
      local += __logf(rs - __builtin_amdgcn_exp2f(d * kScaleAcc)) - d * kInvTAcc;
    }
    float* red = (float*)Xs;
    red[t] = local;
    __syncthreads();
    for (int s2 = 256; s2 > 0; s2 >>= 1) {
      if (t < s2) red[t] += red[t + s2];
      __syncthreads();
    }
    if (t == 0) out[0] = red[0] / (float)N_ROWS;
  }
}

extern "C" void kernel_launch(void* const* d_in, const int* in_sizes, int n_in,
                              void* d_out, int out_size, void* d_ws, size_t ws_size,
                              hipStream_t stream) {
  const float* x = (const float*)d_in[0];
  const float* y = (const float*)d_in[1];
  float* out = (float*)d_out;

  // ws layout: rowsum[N] f32 | diag[N] f32 | done u32(+pad) | xq | yq
  float* rowsum = (float*)d_ws;
  float* diag   = rowsum + N_ROWS;
  unsigned int* done = (unsigned int*)(diag + N_ROWS);
  unsigned char* xq = (unsigned char*)d_ws + 2 * N_ROWS * sizeof(float) + 16;
  unsigned char* yq = xq + (size_t)N_ROWS * D_DIM;

  int cvt_blocks = 2 * N_ROWS * D_DIM / 8 / 256;  // 2048
  cvt_fp8_kernel<<<cvt_blocks, 256, 0, stream>>>(x, y, xq, yq, rowsum, done);

  infonce_gemm<<<256, 512, 0, stream>>>(xq, yq, rowsum, diag, done, out);
}